// Round 17
// baseline (209.078 us; speedup 1.0000x reference)
//
#include <hip/hip_runtime.h>
#include <hip/hip_bf16.h>
#include <math.h>

// ParallelMLayer: x_seq, v_seq = scan over A=sigmoid(F@WA.T+bA),
// dt=softplus(F@Wdt.T+bdt)*0.1*1.5^(d/128), B=(F@WB.T+bB)*dt
// v_t = A_t v_{t-1} + B_t ; x_t = x_{t-1} + dt_t * v_t
//
// R17: scan TLP doubled: NCH=256 (CLEN=16) -> 1024 blocks for pass1/pass3
// (4 blocks/CU, was 2). summ (16MB) relocated into the x_seq region at
// +32MB (dead before pass3 writes x); carry at ws+96MB. GEMM = R16's
// race-free 8-phase (stage distances >=4, waits FIFO-audited). cvt grid-stride.

#define BDIM 4
#define LSEQ 4096
#define DDIM 1024
#define MROWS (BDIM*LSEQ)   // 16384
#define NCH 256             // scan chunks per sequence
#define CLEN (LSEQ/NCH)     // 16
#define N4W (DDIM*DDIM/4)   // 262144 (2^18)
#define N4F (MROWS*DDIM/4)  // 4194304

typedef __attribute__((ext_vector_type(8))) short s16x8;
typedef __attribute__((ext_vector_type(4))) float f32x4;

__device__ inline ushort f2bf(float f) {
    unsigned u = __builtin_bit_cast(unsigned, f);
    unsigned r = (u + 0x7fffu + ((u >> 16) & 1u)) >> 16;
    return (ushort)r;
}
__device__ inline ushort f2h(float f) {
    return __builtin_bit_cast(ushort, (_Float16)f);
}
__device__ inline float h2f(ushort u) {
    return (float)__builtin_bit_cast(_Float16, u);
}

__device__ inline void gld_lds16(const ushort* g, ushort* l) {
    __builtin_amdgcn_global_load_lds(
        (const __attribute__((address_space(1))) void*)g,
        (__attribute__((address_space(3))) void*)l, 16, 0, 0);
}

// ---- fused f32 -> bf16 conversion, grid-stride (2048 blocks) ----
__global__ void cvt_all(const float* __restrict__ force, const float* __restrict__ wa,
                        const float* __restrict__ wb, const float* __restrict__ wdt,
                        ushort* __restrict__ Fb, ushort* __restrict__ Wcat) {
    const int total = N4F + 3 * N4W;
    for (int i = blockIdx.x * 256 + threadIdx.x; i < total; i += 2048 * 256) {
        const float* s; ushort* dst; int j;
        if (i < N4F) {
            s = force; dst = Fb; j = i;
        } else {
            int k = i - N4F;                  // 0 .. 3*N4W-1
            int w = k >> 18;                  // N4W = 2^18
            j = k & (N4W - 1);
            s = (w == 0) ? wa : (w == 1) ? wb : wdt;
            dst = Wcat + (size_t)w * DDIM * DDIM;
        }
        float4 v = reinterpret_cast<const float4*>(s)[j];
        ushort4 o;
        o.x = f2bf(v.x); o.y = f2bf(v.y); o.z = f2bf(v.z); o.w = f2bf(v.w);
        reinterpret_cast<ushort4*>(dst)[j] = o;
    }
}

// ---- 8-phase GEMM: S[i][j] = sum_k F[i][k]*Wcat[j][k] + bias[j] -> fp16 ----
// LDS ushort map: A(par,h) @ par*16384 + h*8192 ; B(par,h) @ 32768 + same.
// Half-tile = [128 rows][64 k-elems]; row r holds phys chunk p at global
// chunk p^(r&7)  (both-sides swizzle, conflict-free: R5-verified).
//
// Stage->read distances (all >= 4 phases):
//   A0,B0 staged P1, first read P5.  B1 staged P2, read P6.  A1 staged P3, read P7.
// FIFO wait audit: end-P1 VMW6 retires prev B1; end-P2 VMW6 retires prev A1;
// end-P3 none; end-P4 VMW4 retires P1's A0,B0. (P5..P8 symmetric.)

#define HBASE(HH) ((HH) < 2 ? (HH) * 8192 : 32768 + ((HH) - 2) * 8192)

#define VMW(n) asm volatile("s_waitcnt vmcnt(" #n ")" ::: "memory")
#define NOVM ((void)0)

// PAR,MG,NG,RDA,STG,HH are literals. TK = staged tile index (runtime).
// STG: 0=none, 1=stage half HH, 2=stage A0+B0 (halves 0 and 2).
#define PHASE(PAR, MG, NG, RDA, STG, HH, TK, VMSTMT)                                 \
  {                                                                                  \
    if (RDA) {                                                                       \
      _Pragma("unroll")                                                              \
      for (int m = 0; m < 4; m++) {                                                  \
        afr[m][0] = *reinterpret_cast<const s16x8*>(                                 \
            &S[(PAR) * 16384 + (MG) * 8192 + rdA + m * 1024 + px0]);                 \
        afr[m][1] = *reinterpret_cast<const s16x8*>(                                 \
            &S[(PAR) * 16384 + (MG) * 8192 + rdA + m * 1024 + px1]);                 \
      }                                                                              \
    }                                                                                \
    _Pragma("unroll")                                                                \
    for (int j = 0; j < 2; j++) {                                                    \
      bfr[j][0] = *reinterpret_cast<const s16x8*>(                                   \
          &S[32768 + (PAR) * 16384 + (NG) * 8192 + rdB + j * 1024 + px0]);           \
      bfr[j][1] = *reinterpret_cast<const s16x8*>(                                   \
          &S[32768 + (PAR) * 16384 + (NG) * 8192 + rdB + j * 1024 + px1]);           \
    }                                                                                \
    if ((STG) == 2) {                                                                \
      ushort* dA0 = &S[((TK) & 1) * 16384 + wid * 512];                              \
      gld_lds16(gsrcs[0][0] + (TK) * 64, dA0);                                       \
      gld_lds16(gsrcs[0][1] + (TK) * 64, dA0 + 4096);                                \
      ushort* dB0 = &S[32768 + ((TK) & 1) * 16384 + wid * 512];                      \
      gld_lds16(gsrcs[2][0] + (TK) * 64, dB0);                                       \
      gld_lds16(gsrcs[2][1] + (TK) * 64, dB0 + 4096);                                \
    } else if ((STG) == 1) {                                                         \
      ushort* d0 = &S[HBASE(HH) + ((TK) & 1) * 16384 + wid * 512];                   \
      gld_lds16(gsrcs[HH][0] + (TK) * 64, d0);                                       \
      gld_lds16(gsrcs[HH][1] + (TK) * 64, d0 + 4096);                                \
    }                                                                                \
    asm volatile("" ::: "memory");                                                   \
    __builtin_amdgcn_s_barrier();                                                    \
    asm volatile("s_waitcnt lgkmcnt(0)" ::: "memory");                               \
    __builtin_amdgcn_sched_barrier(0);                                               \
    __builtin_amdgcn_s_setprio(1);                                                   \
    _Pragma("unroll")                                                                \
    for (int kk = 0; kk < 2; kk++)                                                   \
      _Pragma("unroll")                                                              \
      for (int m = 0; m < 4; m++)                                                    \
        _Pragma("unroll")                                                            \
        for (int j = 0; j < 2; j++)                                                  \
          acc[(MG) * 4 + m][(NG) * 2 + j] = __builtin_amdgcn_mfma_f32_16x16x32_bf16( \
              afr[m][kk], bfr[j][kk], acc[(MG) * 4 + m][(NG) * 2 + j], 0, 0, 0);     \
    __builtin_amdgcn_s_setprio(0);                                                   \
    VMSTMT;                                                                          \
    asm volatile("" ::: "memory");                                                   \
    __builtin_amdgcn_s_barrier();                                                    \
    asm volatile("" ::: "memory");                                                   \
  }

__global__ __launch_bounds__(512) void gemm_fused(
    const ushort* __restrict__ F, const ushort* __restrict__ Wc,
    const float* __restrict__ biasA, const float* __restrict__ biasB,
    const float* __restrict__ biasDt,
    ushort* __restrict__ sA, ushort* __restrict__ sB, ushort* __restrict__ sDt)
{
    __shared__ ushort S[65536];   // 128 KB
    const int t = threadIdx.x;
    // XCD-aware swizzle (768 % 8 == 0 -> bijective)
    const int swz = (blockIdx.x & 7) * 96 + (blockIdx.x >> 3);
    const int bi = swz / 12;     // 0..63  M tiles
    const int bj = swz % 12;     // 0..11  N tiles
    const int lane = t & 63, wid = t >> 6;
    const int wm = wid >> 2, wn = wid & 3;   // 2x4 waves
    const int lr = lane & 15, lg = lane >> 4;

    // staging sources: gload g covers rows g*64 + wid*8 + (lane>>3) of the
    // half-tile; phys chunk lane&7 holds global chunk (lane&7)^(R&7).
    const ushort* gsrcs[4][2];   // [HH][g]; HH: 0=A-h0 1=A-h1 2=B-h0 3=B-h1
#pragma unroll
    for (int h = 0; h < 2; h++)
#pragma unroll
        for (int g = 0; g < 2; g++) {
            const int R = g * 64 + wid * 8 + (lane >> 3);
            const int c8 = ((lane & 7) ^ (R & 7)) * 8;
            gsrcs[h][g]     = F  + ((size_t)(bi * 256 + h * 128 + R)) * DDIM + c8;
            gsrcs[2 + h][g] = Wc + ((size_t)(bj * 256 + h * 128 + R)) * DDIM + c8;
        }

    // read-side constants; rows-in-half: A: wm*64+m*16+lr, B: wn*32+j*16+lr
    const int rdA = (wm * 64 + lr) * 64;
    const int rdB = (wn * 32 + lr) * 64;
    const int px0 = ((0 * 4 + lg) ^ (lr & 7)) * 8;   // kk=0
    const int px1 = ((1 * 4 + lg) ^ (lr & 7)) * 8;   // kk=1

    f32x4 acc[8][4] = {};
    s16x8 afr[4][2], bfr[2][2];

    // prologue: stage tile 0 halves in order A0,B0,B1,A1 (8 loads);
    // VMW(4) retires A0+B0 (read in P1); B1,A1 retire via end-P1/end-P2 waits.
    {
        ushort* d;
        const int HHo[4] = {0, 2, 3, 1};
#pragma unroll
        for (int s_ = 0; s_ < 4; s_++) {
            const int hh = HHo[s_];
            const int hb = (hh < 2) ? hh * 8192 : 32768 + (hh - 2) * 8192;
            d = &S[hb + wid * 512];
            gld_lds16(gsrcs[hh][0], d);
            d = &S[hb + 4096 + wid * 512];
            gld_lds16(gsrcs[hh][1], d);
        }
    }
    VMW(4);
    asm volatile("" ::: "memory");
    __builtin_amdgcn_s_barrier();
    asm volatile("" ::: "memory");

    // main loop: 7 uniform iterations (tiles t0=2i par0, t1=2i+1 par1;
    // stage t1 @P1-P3, t2=2i+2 @P5-P7).
    for (int it = 0; it < 7; ++it) {
        const int t1 = 2 * it + 1;
        const int t2 = 2 * it + 2;
        PHASE(0, 0, 0, 1, 2, 0, t1, VMW(6))   // P1: stage A0+B0(t1)
        PHASE(0, 0, 1, 0, 1, 3, t1, VMW(6))   // P2: stage B1(t1)
        PHASE(0, 1, 0, 1, 1, 1, t1, NOVM)     // P3: stage A1(t1)
        PHASE(0, 1, 1, 0, 0, 0, 0,  VMW(4))   // P4
        PHASE(1, 0, 0, 1, 2, 0, t2, VMW(6))   // P5: stage A0+B0(t2)
        PHASE(1, 0, 1, 0, 1, 3, t2, VMW(6))   // P6: stage B1(t2)
        PHASE(1, 1, 0, 1, 1, 1, t2, NOVM)     // P7: stage A1(t2)
        PHASE(1, 1, 1, 0, 0, 0, 0,  VMW(4))   // P8
    }
    // peeled last iteration (t0=14, t1=15; P5-P8 no staging; drain 4->2->0)
    PHASE(0, 0, 0, 1, 2, 0, 15, VMW(6))
    PHASE(0, 0, 1, 0, 1, 3, 15, VMW(6))
    PHASE(0, 1, 0, 1, 1, 1, 15, NOVM)
    PHASE(0, 1, 1, 0, 0, 0, 0,  VMW(4))   // retires A0,B0(t15)
    PHASE(1, 0, 0, 1, 0, 0, 0,  VMW(2))   // retires B1(t15)
    PHASE(1, 0, 1, 0, 0, 0, 0,  VMW(0))   // retires A1(t15)
    PHASE(1, 1, 0, 1, 0, 0, 0,  NOVM)
    PHASE(1, 1, 1, 0, 0, 0, 0,  NOVM)

    // epilogue: bias-add + fp16 store. C/D: col=lane&15, row=(lane>>4)*4+reg
    const int mat = bj >> 2;                     // 0:A 1:B 2:dt
    const float* bias = (mat == 0) ? biasA : (mat == 1) ? biasB : biasDt;
    ushort* outp = (mat == 0) ? sA : (mat == 1) ? sB : sDt;

#pragma unroll
    for (int ngj = 0; ngj < 4; ngj++) {
        const int ng = ngj >> 1, j = ngj & 1;
        const int d = (bj & 3) * 256 + ng * 128 + wn * 32 + j * 16 + lr;
        const float bb = bias[d];
#pragma unroll
        for (int mgm = 0; mgm < 8; mgm++) {
            const int mg = mgm >> 2, m = mgm & 3;
#pragma unroll
            for (int r = 0; r < 4; r++) {
                const size_t row = (size_t)bi * 256 + mg * 128 + wm * 64 + m * 16 + lg * 4 + r;
                outp[row * DDIM + d] = f2h(acc[mgm][ngj][r] + bb);
            }
        }
    }
}

// activation helpers (scan-side) — HW transcendentals only (R11-verified)
__device__ inline float sigm(float s) {
    return __builtin_amdgcn_rcpf(1.0f + __expf(-s));
}
__device__ inline float softp(float s) {
    return fmaxf(s, 0.0f) + __logf(1.0f + __expf(-fabsf(s)));
}

// ---- scan pass 1: per (b, chunk, d) composite map (a, c, bv, bx) ----
__global__ void scan_pass1(const ushort* __restrict__ sA, const ushort* __restrict__ sB,
                           const ushort* __restrict__ sDt, float4* __restrict__ summ)
{
    const int c = blockIdx.x & (NCH - 1);
    const int b = blockIdx.x >> 8;       // NCH = 256
    const int d4 = threadIdx.x;          // 0..255, covers d = 4*d4..+3
    size_t idx4 = ((size_t)b * LSEQ + (size_t)c * CLEN) * (DDIM / 4) + d4;
    const float scl = 0.1f * exp2f(0.58496250072f * (float)(d4 >> 5)); // 0.1*1.5^(d>>7)
    float a[4] = {1.f,1.f,1.f,1.f}, cc[4] = {}, bv[4] = {}, bx[4] = {};
    for (int i = 0; i < CLEN; i++) {
        ushort4 ua = reinterpret_cast<const ushort4*>(sA)[idx4];
        ushort4 ub = reinterpret_cast<const ushort4*>(sB)[idx4];
        ushort4 ud = reinterpret_cast<const ushort4*>(sDt)[idx4];
        const ushort va[4] = {ua.x, ua.y, ua.z, ua.w};
        const ushort vb[4] = {ub.x, ub.y, ub.z, ub.w};
        const ushort vd[4] = {ud.x, ud.y, ud.z, ud.w};
#pragma unroll
        for (int j = 0; j < 4; j++) {
            const float A  = sigm(h2f(va[j]));
            const float dt = softp(h2f(vd[j])) * scl;
            const float bval = h2f(vb[j]) * dt;
            a[j] *= A;
            cc[j] = fmaf(dt, a[j], cc[j]);
            bv[j] = fmaf(A, bv[j], bval);
            bx[j] = fmaf(dt, bv[j], bx[j]);
        }
        idx4 += DDIM / 4;
    }
    const size_t base = ((size_t)b * NCH + c) * DDIM + (size_t)d4 * 4;
#pragma unroll
    for (int j = 0; j < 4; j++)
        summ[base + j] = make_float4(a[j], cc[j], bv[j], bx[j]);
}

// ---- scan pass 2: serial over chunks per channel -> carry-in (v, x) ----
__global__ void scan_pass2(const float4* __restrict__ summ, float2* __restrict__ carry)
{
    const int idx = blockIdx.x * 256 + threadIdx.x;   // 4096 channels
    const int b = idx >> 10, d = idx & 1023;
    float v = 0.0f, x = 0.0f;
    for (int c = 0; c < NCH; c++) {
        const size_t o = ((size_t)b * NCH + c) * DDIM + d;
        carry[o] = make_float2(v, x);
        float4 s = summ[o];
        x = x + s.y * v + s.w;   // x' = x + c*v + bx (uses OLD v)
        v = s.x * v + s.z;       // v' = a*v + bv
    }
}

// ---- scan pass 3: finalize with carry; write v_seq/x_seq fp32 ----
__global__ void scan_pass3(const ushort* __restrict__ sA, const ushort* __restrict__ sB,
                           const ushort* __restrict__ sDt, const float2* __restrict__ carry,
                           float* __restrict__ VS, float* __restrict__ XS)
{
    const int c = blockIdx.x & (NCH - 1);
    const int b = blockIdx.x >> 8;
    const int d4 = threadIdx.x;
    size_t idx4 = ((size_t)b * LSEQ + (size_t)c * CLEN) * (DDIM / 4) + d4;
    const float scl = 0.1f * exp2f(0.58496250072f * (float)(d4 >> 5));
    const size_t cbase = ((size_t)b * NCH + c) * DDIM + (size_t)d4 * 4;
    f32x4 v, x;
#pragma unroll
    for (int j = 0; j < 4; j++) {
        float2 cr = carry[cbase + j];
        v[j] = cr.x; x[j] = cr.y;
    }
    f32x4* VS4 = (f32x4*)VS;
    f32x4* XS4 = (f32x4*)XS;
    for (int i = 0; i < CLEN; i++) {
        ushort4 ua = reinterpret_cast<const ushort4*>(sA)[idx4];
        ushort4 ub = reinterpret_cast<const ushort4*>(sB)[idx4];
        ushort4 ud = reinterpret_cast<const ushort4*>(sDt)[idx4];
        const ushort va[4] = {ua.x, ua.y, ua.z, ua.w};
        const ushort vb[4] = {ub.x, ub.y, ub.z, ub.w};
        const ushort vd[4] = {ud.x, ud.y, ud.z, ud.w};
#pragma unroll
        for (int j = 0; j < 4; j++) {
            const float A  = sigm(h2f(va[j]));
            const float dt = softp(h2f(vd[j])) * scl;
            v[j] = fmaf(A, v[j], h2f(vb[j]) * dt);
            x[j] = fmaf(dt, v[j], x[j]);
        }
        VS4[idx4] = v;
        XS4[idx4] = x;
        idx4 += DDIM / 4;
    }
}

extern "C" void kernel_launch(void* const* d_in, const int* in_sizes, int n_in,
                              void* d_out, int out_size, void* d_ws, size_t ws_size,
                              hipStream_t stream) {
    const float* force = (const float*)d_in[2];
    const float* WA  = (const float*)d_in[5];
    const float* bA  = (const float*)d_in[6];
    const float* WB  = (const float*)d_in[7];
    const float* bB  = (const float*)d_in[8];
    const float* Wdt = (const float*)d_in[9];
    const float* bdt = (const float*)d_in[10];

    float* xseq = (float*)d_out;                          // [B,L,D] first output
    float* vseq = xseq + (size_t)MROWS * DDIM;            // [B,L,D] second output

    // staging buffers in d_out (liveness: Fb,Wcat dead after gemm; summ
    // written by pass1 (post-gemm), read by pass2, dead before pass3
    // overwrites the x region):
    ushort* Fb   = (ushort*)xseq;                            // [0,32) MB of x region
    float4* summ = (float4*)((char*)xseq + ((size_t)32 << 20)); // [32,48) MB of x region
    ushort* Wcat = (ushort*)vseq;                            //  6 MB of v region

    char* ws = (char*)d_ws;
    ushort* sA    = (ushort*) ws;                            // 32 MB fp16 A preact
    ushort* sB    = (ushort*)(ws + ((size_t)32 << 20));      // 32 MB fp16 B preact
    ushort* sDt   = (ushort*)(ws + ((size_t)64 << 20));      // 32 MB fp16 dt preact
    float2* carry = (float2*)(ws + ((size_t)96 << 20));      //  8 MB chunk carries (ends 104 MB)

    cvt_all<<<2048, 256, 0, stream>>>(force, WA, WB, Wdt, Fb, Wcat);

    gemm_fused<<<768, 512, 0, stream>>>(Fb, Wcat, bA, bB, bdt, sA, sB, sDt);

    scan_pass1<<<BDIM * NCH, 256, 0, stream>>>(sA, sB, sDt, summ);
    scan_pass2<<<16, 256, 0, stream>>>(summ, carry);
    scan_pass3<<<BDIM * NCH, 256, 0, stream>>>(sA, sB, sDt, carry, vseq, xseq);
}

// Round 18
// 208.786 us; speedup vs baseline: 1.0014x; 1.0014x over previous
//
#include <hip/hip_runtime.h>
#include <hip/hip_bf16.h>
#include <math.h>

// ParallelMLayer: x_seq, v_seq = scan over A=sigmoid(F@WA.T+bA),
// dt=softplus(F@Wdt.T+bdt)*0.1*1.5^(d/128), B=(F@WB.T+bB)*dt
// v_t = A_t v_{t-1} + B_t ; x_t = x_{t-1} + dt_t * v_t
//
// R18: NCH reverted to 128 (R17's 256 regressed: pass2 serial doubled,
// CLEN=16 amortized worse). pass1 now computes each 32-chunk as two
// independent 16-step half-summaries interleaved in registers (2x ILP on
// the latency-bound chain), combined associatively at the end.
// GEMM = R16 race-free 8-phase. Layout = R16 (summ/carry in ws).

#define BDIM 4
#define LSEQ 4096
#define DDIM 1024
#define MROWS (BDIM*LSEQ)   // 16384
#define NCH 128             // scan chunks per sequence
#define CLEN (LSEQ/NCH)     // 32
#define HLEN (CLEN/2)       // 16
#define N4W (DDIM*DDIM/4)   // 262144 (2^18)
#define N4F (MROWS*DDIM/4)  // 4194304

typedef __attribute__((ext_vector_type(8))) short s16x8;
typedef __attribute__((ext_vector_type(4))) float f32x4;

__device__ inline ushort f2bf(float f) {
    unsigned u = __builtin_bit_cast(unsigned, f);
    unsigned r = (u + 0x7fffu + ((u >> 16) & 1u)) >> 16;
    return (ushort)r;
}
__device__ inline ushort f2h(float f) {
    return __builtin_bit_cast(ushort, (_Float16)f);
}
__device__ inline float h2f(ushort u) {
    return (float)__builtin_bit_cast(_Float16, u);
}

__device__ inline void gld_lds16(const ushort* g, ushort* l) {
    __builtin_amdgcn_global_load_lds(
        (const __attribute__((address_space(1))) void*)g,
        (__attribute__((address_space(3))) void*)l, 16, 0, 0);
}

// ---- fused f32 -> bf16 conversion, grid-stride (2048 blocks) ----
__global__ void cvt_all(const float* __restrict__ force, const float* __restrict__ wa,
                        const float* __restrict__ wb, const float* __restrict__ wdt,
                        ushort* __restrict__ Fb, ushort* __restrict__ Wcat) {
    const int total = N4F + 3 * N4W;
    for (int i = blockIdx.x * 256 + threadIdx.x; i < total; i += 2048 * 256) {
        const float* s; ushort* dst; int j;
        if (i < N4F) {
            s = force; dst = Fb; j = i;
        } else {
            int k = i - N4F;                  // 0 .. 3*N4W-1
            int w = k >> 18;                  // N4W = 2^18
            j = k & (N4W - 1);
            s = (w == 0) ? wa : (w == 1) ? wb : wdt;
            dst = Wcat + (size_t)w * DDIM * DDIM;
        }
        float4 v = reinterpret_cast<const float4*>(s)[j];
        ushort4 o;
        o.x = f2bf(v.x); o.y = f2bf(v.y); o.z = f2bf(v.z); o.w = f2bf(v.w);
        reinterpret_cast<ushort4*>(dst)[j] = o;
    }
}

// ---- 8-phase GEMM: S[i][j] = sum_k F[i][k]*Wcat[j][k] + bias[j] -> fp16 ----
// LDS ushort map: A(par,h) @ par*16384 + h*8192 ; B(par,h) @ 32768 + same.
// Half-tile = [128 rows][64 k-elems]; row r holds phys chunk p at global
// chunk p^(r&7)  (both-sides swizzle, conflict-free: R5-verified).
//
// Stage->read distances (all >= 4 phases):
//   A0,B0 staged P1, first read P5.  B1 staged P2, read P6.  A1 staged P3, read P7.
// FIFO wait audit: end-P1 VMW6 retires prev B1; end-P2 VMW6 retires prev A1;
// end-P3 none; end-P4 VMW4 retires P1's A0,B0. (P5..P8 symmetric.)

#define HBASE(HH) ((HH) < 2 ? (HH) * 8192 : 32768 + ((HH) - 2) * 8192)

#define VMW(n) asm volatile("s_waitcnt vmcnt(" #n ")" ::: "memory")
#define NOVM ((void)0)

// PAR,MG,NG,RDA,STG,HH are literals. TK = staged tile index (runtime).
// STG: 0=none, 1=stage half HH, 2=stage A0+B0 (halves 0 and 2).
#define PHASE(PAR, MG, NG, RDA, STG, HH, TK, VMSTMT)                                 \
  {                                                                                  \
    if (RDA) {                                                                       \
      _Pragma("unroll")                                                              \
      for (int m = 0; m < 4; m++) {                                                  \
        afr[m][0] = *reinterpret_cast<const s16x8*>(                                 \
            &S[(PAR) * 16384 + (MG) * 8192 + rdA + m * 1024 + px0]);                 \
        afr[m][1] = *reinterpret_cast<const s16x8*>(                                 \
            &S[(PAR) * 16384 + (MG) * 8192 + rdA + m * 1024 + px1]);                 \
      }                                                                              \
    }                                                                                \
    _Pragma("unroll")                                                                \
    for (int j = 0; j < 2; j++) {                                                    \
      bfr[j][0] = *reinterpret_cast<const s16x8*>(                                   \
          &S[32768 + (PAR) * 16384 + (NG) * 8192 + rdB + j * 1024 + px0]);           \
      bfr[j][1] = *reinterpret_cast<const s16x8*>(                                   \
          &S[32768 + (PAR) * 16384 + (NG) * 8192 + rdB + j * 1024 + px1]);           \
    }                                                                                \
    if ((STG) == 2) {                                                                \
      ushort* dA0 = &S[((TK) & 1) * 16384 + wid * 512];                              \
      gld_lds16(gsrcs[0][0] + (TK) * 64, dA0);                                       \
      gld_lds16(gsrcs[0][1] + (TK) * 64, dA0 + 4096);                                \
      ushort* dB0 = &S[32768 + ((TK) & 1) * 16384 + wid * 512];                      \
      gld_lds16(gsrcs[2][0] + (TK) * 64, dB0);                                       \
      gld_lds16(gsrcs[2][1] + (TK) * 64, dB0 + 4096);                                \
    } else if ((STG) == 1) {                                                         \
      ushort* d0 = &S[HBASE(HH) + ((TK) & 1) * 16384 + wid * 512];                   \
      gld_lds16(gsrcs[HH][0] + (TK) * 64, d0);                                       \
      gld_lds16(gsrcs[HH][1] + (TK) * 64, d0 + 4096);                                \
    }                                                                                \
    asm volatile("" ::: "memory");                                                   \
    __builtin_amdgcn_s_barrier();                                                    \
    asm volatile("s_waitcnt lgkmcnt(0)" ::: "memory");                               \
    __builtin_amdgcn_sched_barrier(0);                                               \
    __builtin_amdgcn_s_setprio(1);                                                   \
    _Pragma("unroll")                                                                \
    for (int kk = 0; kk < 2; kk++)                                                   \
      _Pragma("unroll")                                                              \
      for (int m = 0; m < 4; m++)                                                    \
        _Pragma("unroll")                                                            \
        for (int j = 0; j < 2; j++)                                                  \
          acc[(MG) * 4 + m][(NG) * 2 + j] = __builtin_amdgcn_mfma_f32_16x16x32_bf16( \
              afr[m][kk], bfr[j][kk], acc[(MG) * 4 + m][(NG) * 2 + j], 0, 0, 0);     \
    __builtin_amdgcn_s_setprio(0);                                                   \
    VMSTMT;                                                                          \
    asm volatile("" ::: "memory");                                                   \
    __builtin_amdgcn_s_barrier();                                                    \
    asm volatile("" ::: "memory");                                                   \
  }

__global__ __launch_bounds__(512) void gemm_fused(
    const ushort* __restrict__ F, const ushort* __restrict__ Wc,
    const float* __restrict__ biasA, const float* __restrict__ biasB,
    const float* __restrict__ biasDt,
    ushort* __restrict__ sA, ushort* __restrict__ sB, ushort* __restrict__ sDt)
{
    __shared__ ushort S[65536];   // 128 KB
    const int t = threadIdx.x;
    // XCD-aware swizzle (768 % 8 == 0 -> bijective)
    const int swz = (blockIdx.x & 7) * 96 + (blockIdx.x >> 3);
    const int bi = swz / 12;     // 0..63  M tiles
    const int bj = swz % 12;     // 0..11  N tiles
    const int lane = t & 63, wid = t >> 6;
    const int wm = wid >> 2, wn = wid & 3;   // 2x4 waves
    const int lr = lane & 15, lg = lane >> 4;

    // staging sources: gload g covers rows g*64 + wid*8 + (lane>>3) of the
    // half-tile; phys chunk lane&7 holds global chunk (lane&7)^(R&7).
    const ushort* gsrcs[4][2];   // [HH][g]; HH: 0=A-h0 1=A-h1 2=B-h0 3=B-h1
#pragma unroll
    for (int h = 0; h < 2; h++)
#pragma unroll
        for (int g = 0; g < 2; g++) {
            const int R = g * 64 + wid * 8 + (lane >> 3);
            const int c8 = ((lane & 7) ^ (R & 7)) * 8;
            gsrcs[h][g]     = F  + ((size_t)(bi * 256 + h * 128 + R)) * DDIM + c8;
            gsrcs[2 + h][g] = Wc + ((size_t)(bj * 256 + h * 128 + R)) * DDIM + c8;
        }

    // read-side constants; rows-in-half: A: wm*64+m*16+lr, B: wn*32+j*16+lr
    const int rdA = (wm * 64 + lr) * 64;
    const int rdB = (wn * 32 + lr) * 64;
    const int px0 = ((0 * 4 + lg) ^ (lr & 7)) * 8;   // kk=0
    const int px1 = ((1 * 4 + lg) ^ (lr & 7)) * 8;   // kk=1

    f32x4 acc[8][4] = {};
    s16x8 afr[4][2], bfr[2][2];

    // prologue: stage tile 0 halves in order A0,B0,B1,A1 (8 loads);
    // VMW(4) retires A0+B0 (read in P1); B1,A1 retire via end-P1/end-P2 waits.
    {
        ushort* d;
        const int HHo[4] = {0, 2, 3, 1};
#pragma unroll
        for (int s_ = 0; s_ < 4; s_++) {
            const int hh = HHo[s_];
            const int hb = (hh < 2) ? hh * 8192 : 32768 + (hh - 2) * 8192;
            d = &S[hb + wid * 512];
            gld_lds16(gsrcs[hh][0], d);
            d = &S[hb + 4096 + wid * 512];
            gld_lds16(gsrcs[hh][1], d);
        }
    }
    VMW(4);
    asm volatile("" ::: "memory");
    __builtin_amdgcn_s_barrier();
    asm volatile("" ::: "memory");

    // main loop: 7 uniform iterations (tiles t0=2i par0, t1=2i+1 par1;
    // stage t1 @P1-P3, t2=2i+2 @P5-P7).
    for (int it = 0; it < 7; ++it) {
        const int t1 = 2 * it + 1;
        const int t2 = 2 * it + 2;
        PHASE(0, 0, 0, 1, 2, 0, t1, VMW(6))   // P1: stage A0+B0(t1)
        PHASE(0, 0, 1, 0, 1, 3, t1, VMW(6))   // P2: stage B1(t1)
        PHASE(0, 1, 0, 1, 1, 1, t1, NOVM)     // P3: stage A1(t1)
        PHASE(0, 1, 1, 0, 0, 0, 0,  VMW(4))   // P4
        PHASE(1, 0, 0, 1, 2, 0, t2, VMW(6))   // P5: stage A0+B0(t2)
        PHASE(1, 0, 1, 0, 1, 3, t2, VMW(6))   // P6: stage B1(t2)
        PHASE(1, 1, 0, 1, 1, 1, t2, NOVM)     // P7: stage A1(t2)
        PHASE(1, 1, 1, 0, 0, 0, 0,  VMW(4))   // P8
    }
    // peeled last iteration (t0=14, t1=15; P5-P8 no staging; drain 4->2->0)
    PHASE(0, 0, 0, 1, 2, 0, 15, VMW(6))
    PHASE(0, 0, 1, 0, 1, 3, 15, VMW(6))
    PHASE(0, 1, 0, 1, 1, 1, 15, NOVM)
    PHASE(0, 1, 1, 0, 0, 0, 0,  VMW(4))   // retires A0,B0(t15)
    PHASE(1, 0, 0, 1, 0, 0, 0,  VMW(2))   // retires B1(t15)
    PHASE(1, 0, 1, 0, 0, 0, 0,  VMW(0))   // retires A1(t15)
    PHASE(1, 1, 0, 1, 0, 0, 0,  NOVM)
    PHASE(1, 1, 1, 0, 0, 0, 0,  NOVM)

    // epilogue: bias-add + fp16 store. C/D: col=lane&15, row=(lane>>4)*4+reg
    const int mat = bj >> 2;                     // 0:A 1:B 2:dt
    const float* bias = (mat == 0) ? biasA : (mat == 1) ? biasB : biasDt;
    ushort* outp = (mat == 0) ? sA : (mat == 1) ? sB : sDt;

#pragma unroll
    for (int ngj = 0; ngj < 4; ngj++) {
        const int ng = ngj >> 1, j = ngj & 1;
        const int d = (bj & 3) * 256 + ng * 128 + wn * 32 + j * 16 + lr;
        const float bb = bias[d];
#pragma unroll
        for (int mgm = 0; mgm < 8; mgm++) {
            const int mg = mgm >> 2, m = mgm & 3;
#pragma unroll
            for (int r = 0; r < 4; r++) {
                const size_t row = (size_t)bi * 256 + mg * 128 + wm * 64 + m * 16 + lg * 4 + r;
                outp[row * DDIM + d] = f2h(acc[mgm][ngj][r] + bb);
            }
        }
    }
}

// activation helpers (scan-side) — HW transcendentals only (R11-verified)
__device__ inline float sigm(float s) {
    return __builtin_amdgcn_rcpf(1.0f + __expf(-s));
}
__device__ inline float softp(float s) {
    return fmaxf(s, 0.0f) + __logf(1.0f + __expf(-fabsf(s)));
}

// ---- scan pass 1: two independent 16-step half-summaries per 32-chunk,
// interleaved for ILP (latency-bound kernel), combined associatively ----
__global__ void scan_pass1(const ushort* __restrict__ sA, const ushort* __restrict__ sB,
                           const ushort* __restrict__ sDt, float4* __restrict__ summ)
{
    const int c = blockIdx.x & (NCH - 1);
    const int b = blockIdx.x >> 7;       // NCH = 128
    const int d4 = threadIdx.x;          // 0..255, covers d = 4*d4..+3
    size_t i1 = ((size_t)b * LSEQ + (size_t)c * CLEN) * (DDIM / 4) + d4;
    size_t i2 = i1 + (size_t)HLEN * (DDIM / 4);
    const float scl = 0.1f * exp2f(0.58496250072f * (float)(d4 >> 5)); // 0.1*1.5^(d>>7)
    float a1[4] = {1.f,1.f,1.f,1.f}, c1[4] = {}, v1[4] = {}, x1[4] = {};
    float a2[4] = {1.f,1.f,1.f,1.f}, c2[4] = {}, v2[4] = {}, x2[4] = {};
    for (int i = 0; i < HLEN; i++) {
        ushort4 ua1 = reinterpret_cast<const ushort4*>(sA)[i1];
        ushort4 ub1 = reinterpret_cast<const ushort4*>(sB)[i1];
        ushort4 ud1 = reinterpret_cast<const ushort4*>(sDt)[i1];
        ushort4 ua2 = reinterpret_cast<const ushort4*>(sA)[i2];
        ushort4 ub2 = reinterpret_cast<const ushort4*>(sB)[i2];
        ushort4 ud2 = reinterpret_cast<const ushort4*>(sDt)[i2];
        const ushort va1[4] = {ua1.x, ua1.y, ua1.z, ua1.w};
        const ushort vb1[4] = {ub1.x, ub1.y, ub1.z, ub1.w};
        const ushort vd1[4] = {ud1.x, ud1.y, ud1.z, ud1.w};
        const ushort va2[4] = {ua2.x, ua2.y, ua2.z, ua2.w};
        const ushort vb2[4] = {ub2.x, ub2.y, ub2.z, ub2.w};
        const ushort vd2[4] = {ud2.x, ud2.y, ud2.z, ud2.w};
#pragma unroll
        for (int j = 0; j < 4; j++) {
            const float A1  = sigm(h2f(va1[j]));
            const float dt1 = softp(h2f(vd1[j])) * scl;
            a1[j] *= A1;
            c1[j] = fmaf(dt1, a1[j], c1[j]);
            v1[j] = fmaf(A1, v1[j], h2f(vb1[j]) * dt1);
            x1[j] = fmaf(dt1, v1[j], x1[j]);
            const float A2  = sigm(h2f(va2[j]));
            const float dt2 = softp(h2f(vd2[j])) * scl;
            a2[j] *= A2;
            c2[j] = fmaf(dt2, a2[j], c2[j]);
            v2[j] = fmaf(A2, v2[j], h2f(vb2[j]) * dt2);
            x2[j] = fmaf(dt2, v2[j], x2[j]);
        }
        i1 += DDIM / 4;
        i2 += DDIM / 4;
    }
    // combine S1 then S2: a=a1*a2; c=c1+c2*a1; bv=a2*bv1+bv2; bx=x1+c2*bv1+x2
    const size_t base = ((size_t)b * NCH + c) * DDIM + (size_t)d4 * 4;
#pragma unroll
    for (int j = 0; j < 4; j++) {
        const float af = a1[j] * a2[j];
        const float cf = fmaf(c2[j], a1[j], c1[j]);
        const float bvf = fmaf(a2[j], v1[j], v2[j]);
        const float bxf = x1[j] + fmaf(c2[j], v1[j], x2[j]);
        summ[base + j] = make_float4(af, cf, bvf, bxf);
    }
}

// ---- scan pass 2: serial over chunks per channel -> carry-in (v, x) ----
__global__ void scan_pass2(const float4* __restrict__ summ, float2* __restrict__ carry)
{
    const int idx = blockIdx.x * 256 + threadIdx.x;   // 4096 channels
    const int b = idx >> 10, d = idx & 1023;
    float v = 0.0f, x = 0.0f;
    for (int c = 0; c < NCH; c++) {
        const size_t o = ((size_t)b * NCH + c) * DDIM + d;
        carry[o] = make_float2(v, x);
        float4 s = summ[o];
        x = x + s.y * v + s.w;   // x' = x + c*v + bx (uses OLD v)
        v = s.x * v + s.z;       // v' = a*v + bv
    }
}

// ---- scan pass 3: finalize with carry; write v_seq/x_seq fp32 ----
__global__ void scan_pass3(const ushort* __restrict__ sA, const ushort* __restrict__ sB,
                           const ushort* __restrict__ sDt, const float2* __restrict__ carry,
                           float* __restrict__ VS, float* __restrict__ XS)
{
    const int c = blockIdx.x & (NCH - 1);
    const int b = blockIdx.x >> 7;
    const int d4 = threadIdx.x;
    size_t idx4 = ((size_t)b * LSEQ + (size_t)c * CLEN) * (DDIM / 4) + d4;
    const float scl = 0.1f * exp2f(0.58496250072f * (float)(d4 >> 5));
    const size_t cbase = ((size_t)b * NCH + c) * DDIM + (size_t)d4 * 4;
    f32x4 v, x;
#pragma unroll
    for (int j = 0; j < 4; j++) {
        float2 cr = carry[cbase + j];
        v[j] = cr.x; x[j] = cr.y;
    }
    f32x4* VS4 = (f32x4*)VS;
    f32x4* XS4 = (f32x4*)XS;
    for (int i = 0; i < CLEN; i++) {
        ushort4 ua = reinterpret_cast<const ushort4*>(sA)[idx4];
        ushort4 ub = reinterpret_cast<const ushort4*>(sB)[idx4];
        ushort4 ud = reinterpret_cast<const ushort4*>(sDt)[idx4];
        const ushort va[4] = {ua.x, ua.y, ua.z, ua.w};
        const ushort vb[4] = {ub.x, ub.y, ub.z, ub.w};
        const ushort vd[4] = {ud.x, ud.y, ud.z, ud.w};
#pragma unroll
        for (int j = 0; j < 4; j++) {
            const float A  = sigm(h2f(va[j]));
            const float dt = softp(h2f(vd[j])) * scl;
            v[j] = fmaf(A, v[j], h2f(vb[j]) * dt);
            x[j] = fmaf(dt, v[j], x[j]);
        }
        VS4[idx4] = v;
        XS4[idx4] = x;
        idx4 += DDIM / 4;
    }
}

extern "C" void kernel_launch(void* const* d_in, const int* in_sizes, int n_in,
                              void* d_out, int out_size, void* d_ws, size_t ws_size,
                              hipStream_t stream) {
    const float* force = (const float*)d_in[2];
    const float* WA  = (const float*)d_in[5];
    const float* bA  = (const float*)d_in[6];
    const float* WB  = (const float*)d_in[7];
    const float* bB  = (const float*)d_in[8];
    const float* Wdt = (const float*)d_in[9];
    const float* bdt = (const float*)d_in[10];

    float* xseq = (float*)d_out;                          // [B,L,D] first output
    float* vseq = xseq + (size_t)MROWS * DDIM;            // [B,L,D] second output

    // bf16 staging buffers live in d_out (dead before pass3 writes there):
    ushort* Fb   = (ushort*)xseq;   // 32 MB bf16 force in x region
    ushort* Wcat = (ushort*)vseq;   //  6 MB bf16 [WA;WB;Wdt] in v region

    char* ws = (char*)d_ws;
    ushort* sA    = (ushort*) ws;                            // 32 MB fp16 A preact
    ushort* sB    = (ushort*)(ws + ((size_t)32 << 20));      // 32 MB fp16 B preact
    ushort* sDt   = (ushort*)(ws + ((size_t)64 << 20));      // 32 MB fp16 dt preact
    float4* summ  = (float4*)(ws + ((size_t)96 << 20));      //  8 MB chunk summaries
    float2* carry = (float2*)(ws + ((size_t)104 << 20));     //  4 MB chunk carries (ends 108 MB)

    cvt_all<<<2048, 256, 0, stream>>>(force, WA, WB, Wdt, Fb, Wcat);

    gemm_fused<<<768, 512, 0, stream>>>(Fb, Wcat, bA, bB, bdt, sA, sB, sDt);

    scan_pass1<<<BDIM * NCH, 256, 0, stream>>>(sA, sB, sDt, summ);
    scan_pass2<<<16, 256, 0, stream>>>(summ, carry);
    scan_pass3<<<BDIM * NCH, 256, 0, stream>>>(sA, sB, sDt, carry, vseq, xseq);
}

// Round 19
// 202.733 us; speedup vs baseline: 1.0313x; 1.0299x over previous
//
#include <hip/hip_runtime.h>
#include <hip/hip_bf16.h>
#include <math.h>

// ParallelMLayer: x_seq, v_seq = scan over A=sigmoid(F@WA.T+bA),
// dt=softplus(F@Wdt.T+bdt)*0.1*1.5^(d/128), B=(F@WB.T+bB)*dt
// v_t = A_t v_{t-1} + B_t ; x_t = x_{t-1} + dt_t * v_t
//
// R19 = R16 revert (best verified: 203.9 us, absmax 4.0). R17 (scan TLP)
// and R18 (scan ILP) both regressed ~5 us; restoring the optimum.
// GEMM: race-free 8-phase counted-vmcnt (stage distances >=4, FIFO-audited
// waits). Scans: NCH=128 serial per-thread, HW transcendentals.

#define BDIM 4
#define LSEQ 4096
#define DDIM 1024
#define MROWS (BDIM*LSEQ)   // 16384
#define NCH 128             // scan chunks per sequence
#define CLEN (LSEQ/NCH)     // 32
#define N4W (DDIM*DDIM/4)   // 262144 (2^18)
#define N4F (MROWS*DDIM/4)  // 4194304

typedef __attribute__((ext_vector_type(8))) short s16x8;
typedef __attribute__((ext_vector_type(4))) float f32x4;

__device__ inline ushort f2bf(float f) {
    unsigned u = __builtin_bit_cast(unsigned, f);
    unsigned r = (u + 0x7fffu + ((u >> 16) & 1u)) >> 16;
    return (ushort)r;
}
__device__ inline ushort f2h(float f) {
    return __builtin_bit_cast(ushort, (_Float16)f);
}
__device__ inline float h2f(ushort u) {
    return (float)__builtin_bit_cast(_Float16, u);
}

__device__ inline void gld_lds16(const ushort* g, ushort* l) {
    __builtin_amdgcn_global_load_lds(
        (const __attribute__((address_space(1))) void*)g,
        (__attribute__((address_space(3))) void*)l, 16, 0, 0);
}

// ---- fused f32 -> bf16 conversion, grid-stride (2048 blocks) ----
__global__ void cvt_all(const float* __restrict__ force, const float* __restrict__ wa,
                        const float* __restrict__ wb, const float* __restrict__ wdt,
                        ushort* __restrict__ Fb, ushort* __restrict__ Wcat) {
    const int total = N4F + 3 * N4W;
    for (int i = blockIdx.x * 256 + threadIdx.x; i < total; i += 2048 * 256) {
        const float* s; ushort* dst; int j;
        if (i < N4F) {
            s = force; dst = Fb; j = i;
        } else {
            int k = i - N4F;                  // 0 .. 3*N4W-1
            int w = k >> 18;                  // N4W = 2^18
            j = k & (N4W - 1);
            s = (w == 0) ? wa : (w == 1) ? wb : wdt;
            dst = Wcat + (size_t)w * DDIM * DDIM;
        }
        float4 v = reinterpret_cast<const float4*>(s)[j];
        ushort4 o;
        o.x = f2bf(v.x); o.y = f2bf(v.y); o.z = f2bf(v.z); o.w = f2bf(v.w);
        reinterpret_cast<ushort4*>(dst)[j] = o;
    }
}

// ---- 8-phase GEMM: S[i][j] = sum_k F[i][k]*Wcat[j][k] + bias[j] -> fp16 ----
// LDS ushort map: A(par,h) @ par*16384 + h*8192 ; B(par,h) @ 32768 + same.
// Half-tile = [128 rows][64 k-elems]; row r holds phys chunk p at global
// chunk p^(r&7)  (both-sides swizzle, conflict-free: R5-verified).
//
// Stage->read distances (all >= 4 phases):
//   A0,B0 staged P1, first read P5.  B1 staged P2, read P6.  A1 staged P3, read P7.
// FIFO wait audit: end-P1 VMW6 retires prev B1; end-P2 VMW6 retires prev A1;
// end-P3 none; end-P4 VMW4 retires P1's A0,B0. (P5..P8 symmetric.)

#define HBASE(HH) ((HH) < 2 ? (HH) * 8192 : 32768 + ((HH) - 2) * 8192)

#define VMW(n) asm volatile("s_waitcnt vmcnt(" #n ")" ::: "memory")
#define NOVM ((void)0)

// PAR,MG,NG,RDA,STG,HH are literals. TK = staged tile index (runtime).
// STG: 0=none, 1=stage half HH, 2=stage A0+B0 (halves 0 and 2).
#define PHASE(PAR, MG, NG, RDA, STG, HH, TK, VMSTMT)                                 \
  {                                                                                  \
    if (RDA) {                                                                       \
      _Pragma("unroll")                                                              \
      for (int m = 0; m < 4; m++) {                                                  \
        afr[m][0] = *reinterpret_cast<const s16x8*>(                                 \
            &S[(PAR) * 16384 + (MG) * 8192 + rdA + m * 1024 + px0]);                 \
        afr[m][1] = *reinterpret_cast<const s16x8*>(                                 \
            &S[(PAR) * 16384 + (MG) * 8192 + rdA + m * 1024 + px1]);                 \
      }                                                                              \
    }                                                                                \
    _Pragma("unroll")                                                                \
    for (int j = 0; j < 2; j++) {                                                    \
      bfr[j][0] = *reinterpret_cast<const s16x8*>(                                   \
          &S[32768 + (PAR) * 16384 + (NG) * 8192 + rdB + j * 1024 + px0]);           \
      bfr[j][1] = *reinterpret_cast<const s16x8*>(                                   \
          &S[32768 + (PAR) * 16384 + (NG) * 8192 + rdB + j * 1024 + px1]);           \
    }                                                                                \
    if ((STG) == 2) {                                                                \
      ushort* dA0 = &S[((TK) & 1) * 16384 + wid * 512];                              \
      gld_lds16(gsrcs[0][0] + (TK) * 64, dA0);                                       \
      gld_lds16(gsrcs[0][1] + (TK) * 64, dA0 + 4096);                                \
      ushort* dB0 = &S[32768 + ((TK) & 1) * 16384 + wid * 512];                      \
      gld_lds16(gsrcs[2][0] + (TK) * 64, dB0);                                       \
      gld_lds16(gsrcs[2][1] + (TK) * 64, dB0 + 4096);                                \
    } else if ((STG) == 1) {                                                         \
      ushort* d0 = &S[HBASE(HH) + ((TK) & 1) * 16384 + wid * 512];                   \
      gld_lds16(gsrcs[HH][0] + (TK) * 64, d0);                                       \
      gld_lds16(gsrcs[HH][1] + (TK) * 64, d0 + 4096);                                \
    }                                                                                \
    asm volatile("" ::: "memory");                                                   \
    __builtin_amdgcn_s_barrier();                                                    \
    asm volatile("s_waitcnt lgkmcnt(0)" ::: "memory");                               \
    __builtin_amdgcn_sched_barrier(0);                                               \
    __builtin_amdgcn_s_setprio(1);                                                   \
    _Pragma("unroll")                                                                \
    for (int kk = 0; kk < 2; kk++)                                                   \
      _Pragma("unroll")                                                              \
      for (int m = 0; m < 4; m++)                                                    \
        _Pragma("unroll")                                                            \
        for (int j = 0; j < 2; j++)                                                  \
          acc[(MG) * 4 + m][(NG) * 2 + j] = __builtin_amdgcn_mfma_f32_16x16x32_bf16( \
              afr[m][kk], bfr[j][kk], acc[(MG) * 4 + m][(NG) * 2 + j], 0, 0, 0);     \
    __builtin_amdgcn_s_setprio(0);                                                   \
    VMSTMT;                                                                          \
    asm volatile("" ::: "memory");                                                   \
    __builtin_amdgcn_s_barrier();                                                    \
    asm volatile("" ::: "memory");                                                   \
  }

__global__ __launch_bounds__(512) void gemm_fused(
    const ushort* __restrict__ F, const ushort* __restrict__ Wc,
    const float* __restrict__ biasA, const float* __restrict__ biasB,
    const float* __restrict__ biasDt,
    ushort* __restrict__ sA, ushort* __restrict__ sB, ushort* __restrict__ sDt)
{
    __shared__ ushort S[65536];   // 128 KB
    const int t = threadIdx.x;
    // XCD-aware swizzle (768 % 8 == 0 -> bijective)
    const int swz = (blockIdx.x & 7) * 96 + (blockIdx.x >> 3);
    const int bi = swz / 12;     // 0..63  M tiles
    const int bj = swz % 12;     // 0..11  N tiles
    const int lane = t & 63, wid = t >> 6;
    const int wm = wid >> 2, wn = wid & 3;   // 2x4 waves
    const int lr = lane & 15, lg = lane >> 4;

    // staging sources: gload g covers rows g*64 + wid*8 + (lane>>3) of the
    // half-tile; phys chunk lane&7 holds global chunk (lane&7)^(R&7).
    const ushort* gsrcs[4][2];   // [HH][g]; HH: 0=A-h0 1=A-h1 2=B-h0 3=B-h1
#pragma unroll
    for (int h = 0; h < 2; h++)
#pragma unroll
        for (int g = 0; g < 2; g++) {
            const int R = g * 64 + wid * 8 + (lane >> 3);
            const int c8 = ((lane & 7) ^ (R & 7)) * 8;
            gsrcs[h][g]     = F  + ((size_t)(bi * 256 + h * 128 + R)) * DDIM + c8;
            gsrcs[2 + h][g] = Wc + ((size_t)(bj * 256 + h * 128 + R)) * DDIM + c8;
        }

    // read-side constants; rows-in-half: A: wm*64+m*16+lr, B: wn*32+j*16+lr
    const int rdA = (wm * 64 + lr) * 64;
    const int rdB = (wn * 32 + lr) * 64;
    const int px0 = ((0 * 4 + lg) ^ (lr & 7)) * 8;   // kk=0
    const int px1 = ((1 * 4 + lg) ^ (lr & 7)) * 8;   // kk=1

    f32x4 acc[8][4] = {};
    s16x8 afr[4][2], bfr[2][2];

    // prologue: stage tile 0 halves in order A0,B0,B1,A1 (8 loads);
    // VMW(4) retires A0+B0 (read in P1); B1,A1 retire via end-P1/end-P2 waits.
    {
        ushort* d;
        const int HHo[4] = {0, 2, 3, 1};
#pragma unroll
        for (int s_ = 0; s_ < 4; s_++) {
            const int hh = HHo[s_];
            const int hb = (hh < 2) ? hh * 8192 : 32768 + (hh - 2) * 8192;
            d = &S[hb + wid * 512];
            gld_lds16(gsrcs[hh][0], d);
            d = &S[hb + 4096 + wid * 512];
            gld_lds16(gsrcs[hh][1], d);
        }
    }
    VMW(4);
    asm volatile("" ::: "memory");
    __builtin_amdgcn_s_barrier();
    asm volatile("" ::: "memory");

    // main loop: 7 uniform iterations (tiles t0=2i par0, t1=2i+1 par1;
    // stage t1 @P1-P3, t2=2i+2 @P5-P7).
    for (int it = 0; it < 7; ++it) {
        const int t1 = 2 * it + 1;
        const int t2 = 2 * it + 2;
        PHASE(0, 0, 0, 1, 2, 0, t1, VMW(6))   // P1: stage A0+B0(t1)
        PHASE(0, 0, 1, 0, 1, 3, t1, VMW(6))   // P2: stage B1(t1)
        PHASE(0, 1, 0, 1, 1, 1, t1, NOVM)     // P3: stage A1(t1)
        PHASE(0, 1, 1, 0, 0, 0, 0,  VMW(4))   // P4
        PHASE(1, 0, 0, 1, 2, 0, t2, VMW(6))   // P5: stage A0+B0(t2)
        PHASE(1, 0, 1, 0, 1, 3, t2, VMW(6))   // P6: stage B1(t2)
        PHASE(1, 1, 0, 1, 1, 1, t2, NOVM)     // P7: stage A1(t2)
        PHASE(1, 1, 1, 0, 0, 0, 0,  VMW(4))   // P8
    }
    // peeled last iteration (t0=14, t1=15; P5-P8 no staging; drain 4->2->0)
    PHASE(0, 0, 0, 1, 2, 0, 15, VMW(6))
    PHASE(0, 0, 1, 0, 1, 3, 15, VMW(6))
    PHASE(0, 1, 0, 1, 1, 1, 15, NOVM)
    PHASE(0, 1, 1, 0, 0, 0, 0,  VMW(4))   // retires A0,B0(t15)
    PHASE(1, 0, 0, 1, 0, 0, 0,  VMW(2))   // retires B1(t15)
    PHASE(1, 0, 1, 0, 0, 0, 0,  VMW(0))   // retires A1(t15)
    PHASE(1, 1, 0, 1, 0, 0, 0,  NOVM)
    PHASE(1, 1, 1, 0, 0, 0, 0,  NOVM)

    // epilogue: bias-add + fp16 store. C/D: col=lane&15, row=(lane>>4)*4+reg
    const int mat = bj >> 2;                     // 0:A 1:B 2:dt
    const float* bias = (mat == 0) ? biasA : (mat == 1) ? biasB : biasDt;
    ushort* outp = (mat == 0) ? sA : (mat == 1) ? sB : sDt;

#pragma unroll
    for (int ngj = 0; ngj < 4; ngj++) {
        const int ng = ngj >> 1, j = ngj & 1;
        const int d = (bj & 3) * 256 + ng * 128 + wn * 32 + j * 16 + lr;
        const float bb = bias[d];
#pragma unroll
        for (int mgm = 0; mgm < 8; mgm++) {
            const int mg = mgm >> 2, m = mgm & 3;
#pragma unroll
            for (int r = 0; r < 4; r++) {
                const size_t row = (size_t)bi * 256 + mg * 128 + wm * 64 + m * 16 + lg * 4 + r;
                outp[row * DDIM + d] = f2h(acc[mgm][ngj][r] + bb);
            }
        }
    }
}

// activation helpers (scan-side) — HW transcendentals only (R11-verified)
__device__ inline float sigm(float s) {
    return __builtin_amdgcn_rcpf(1.0f + __expf(-s));
}
__device__ inline float softp(float s) {
    return fmaxf(s, 0.0f) + __logf(1.0f + __expf(-fabsf(s)));
}

// ---- scan pass 1: per (b, chunk, d) composite map (a, c, bv, bx) ----
__global__ void scan_pass1(const ushort* __restrict__ sA, const ushort* __restrict__ sB,
                           const ushort* __restrict__ sDt, float4* __restrict__ summ)
{
    const int c = blockIdx.x & (NCH - 1);
    const int b = blockIdx.x >> 7;       // NCH = 128
    const int d4 = threadIdx.x;          // 0..255, covers d = 4*d4..+3
    size_t idx4 = ((size_t)b * LSEQ + (size_t)c * CLEN) * (DDIM / 4) + d4;
    const float scl = 0.1f * exp2f(0.58496250072f * (float)(d4 >> 5)); // 0.1*1.5^(d>>7)
    float a[4] = {1.f,1.f,1.f,1.f}, cc[4] = {}, bv[4] = {}, bx[4] = {};
    for (int i = 0; i < CLEN; i++) {
        ushort4 ua = reinterpret_cast<const ushort4*>(sA)[idx4];
        ushort4 ub = reinterpret_cast<const ushort4*>(sB)[idx4];
        ushort4 ud = reinterpret_cast<const ushort4*>(sDt)[idx4];
        const ushort va[4] = {ua.x, ua.y, ua.z, ua.w};
        const ushort vb[4] = {ub.x, ub.y, ub.z, ub.w};
        const ushort vd[4] = {ud.x, ud.y, ud.z, ud.w};
#pragma unroll
        for (int j = 0; j < 4; j++) {
            const float A  = sigm(h2f(va[j]));
            const float dt = softp(h2f(vd[j])) * scl;
            const float bval = h2f(vb[j]) * dt;
            a[j] *= A;
            cc[j] = fmaf(dt, a[j], cc[j]);
            bv[j] = fmaf(A, bv[j], bval);
            bx[j] = fmaf(dt, bv[j], bx[j]);
        }
        idx4 += DDIM / 4;
    }
    const size_t base = ((size_t)b * NCH + c) * DDIM + (size_t)d4 * 4;
#pragma unroll
    for (int j = 0; j < 4; j++)
        summ[base + j] = make_float4(a[j], cc[j], bv[j], bx[j]);
}

// ---- scan pass 2: serial over chunks per channel -> carry-in (v, x) ----
__global__ void scan_pass2(const float4* __restrict__ summ, float2* __restrict__ carry)
{
    const int idx = blockIdx.x * 256 + threadIdx.x;   // 4096 channels
    const int b = idx >> 10, d = idx & 1023;
    float v = 0.0f, x = 0.0f;
    for (int c = 0; c < NCH; c++) {
        const size_t o = ((size_t)b * NCH + c) * DDIM + d;
        carry[o] = make_float2(v, x);
        float4 s = summ[o];
        x = x + s.y * v + s.w;   // x' = x + c*v + bx (uses OLD v)
        v = s.x * v + s.z;       // v' = a*v + bv
    }
}

// ---- scan pass 3: finalize with carry; write v_seq/x_seq fp32 ----
__global__ void scan_pass3(const ushort* __restrict__ sA, const ushort* __restrict__ sB,
                           const ushort* __restrict__ sDt, const float2* __restrict__ carry,
                           float* __restrict__ VS, float* __restrict__ XS)
{
    const int c = blockIdx.x & (NCH - 1);
    const int b = blockIdx.x >> 7;
    const int d4 = threadIdx.x;
    size_t idx4 = ((size_t)b * LSEQ + (size_t)c * CLEN) * (DDIM / 4) + d4;
    const float scl = 0.1f * exp2f(0.58496250072f * (float)(d4 >> 5));
    const size_t cbase = ((size_t)b * NCH + c) * DDIM + (size_t)d4 * 4;
    f32x4 v, x;
#pragma unroll
    for (int j = 0; j < 4; j++) {
        float2 cr = carry[cbase + j];
        v[j] = cr.x; x[j] = cr.y;
    }
    f32x4* VS4 = (f32x4*)VS;
    f32x4* XS4 = (f32x4*)XS;
    for (int i = 0; i < CLEN; i++) {
        ushort4 ua = reinterpret_cast<const ushort4*>(sA)[idx4];
        ushort4 ub = reinterpret_cast<const ushort4*>(sB)[idx4];
        ushort4 ud = reinterpret_cast<const ushort4*>(sDt)[idx4];
        const ushort va[4] = {ua.x, ua.y, ua.z, ua.w};
        const ushort vb[4] = {ub.x, ub.y, ub.z, ub.w};
        const ushort vd[4] = {ud.x, ud.y, ud.z, ud.w};
#pragma unroll
        for (int j = 0; j < 4; j++) {
            const float A  = sigm(h2f(va[j]));
            const float dt = softp(h2f(vd[j])) * scl;
            v[j] = fmaf(A, v[j], h2f(vb[j]) * dt);
            x[j] = fmaf(dt, v[j], x[j]);
        }
        VS4[idx4] = v;
        XS4[idx4] = x;
        idx4 += DDIM / 4;
    }
}

extern "C" void kernel_launch(void* const* d_in, const int* in_sizes, int n_in,
                              void* d_out, int out_size, void* d_ws, size_t ws_size,
                              hipStream_t stream) {
    const float* force = (const float*)d_in[2];
    const float* WA  = (const float*)d_in[5];
    const float* bA  = (const float*)d_in[6];
    const float* WB  = (const float*)d_in[7];
    const float* bB  = (const float*)d_in[8];
    const float* Wdt = (const float*)d_in[9];
    const float* bdt = (const float*)d_in[10];

    float* xseq = (float*)d_out;                          // [B,L,D] first output
    float* vseq = xseq + (size_t)MROWS * DDIM;            // [B,L,D] second output

    // bf16 staging buffers live in d_out (dead before pass3 writes there):
    ushort* Fb   = (ushort*)xseq;   // 32 MB bf16 force in x region
    ushort* Wcat = (ushort*)vseq;   //  6 MB bf16 [WA;WB;Wdt] in v region

    char* ws = (char*)d_ws;
    ushort* sA    = (ushort*) ws;                            // 32 MB fp16 A preact
    ushort* sB    = (ushort*)(ws + ((size_t)32 << 20));      // 32 MB fp16 B preact
    ushort* sDt   = (ushort*)(ws + ((size_t)64 << 20));      // 32 MB fp16 dt preact
    float4* summ  = (float4*)(ws + ((size_t)96 << 20));      //  8 MB chunk summaries
    float2* carry = (float2*)(ws + ((size_t)104 << 20));     //  4 MB chunk carries (ends 108 MB)

    cvt_all<<<2048, 256, 0, stream>>>(force, WA, WB, Wdt, Fb, Wcat);

    gemm_fused<<<768, 512, 0, stream>>>(Fb, Wcat, bA, bB, bdt, sA, sB, sDt);

    scan_pass1<<<BDIM * NCH, 256, 0, stream>>>(sA, sB, sDt, summ);
    scan_pass2<<<16, 256, 0, stream>>>(summ, carry);
    scan_pass3<<<BDIM * NCH, 256, 0, stream>>>(sA, sB, sDt, carry, vseq, xseq);
}